// Round 13
// baseline (1027.982 us; speedup 1.0000x reference)
//
#include <hip/hip_runtime.h>

#define DEV static __device__ __forceinline__

DEV float sqdist(float dx, float dy, float dz) {
    // ((dx*dx + dy*dy) + dz*dz) with no FMA contraction — must match numpy f32
    return __fadd_rn(__fadd_rn(__fmul_rn(dx, dx), __fmul_rn(dy, dy)), __fmul_rn(dz, dz));
}

DEV void fma4(float4& acc, float h, const float4& w) {
    acc.x = fmaf(h, w.x, acc.x); acc.y = fmaf(h, w.y, acc.y);
    acc.z = fmaf(h, w.z, acc.z); acc.w = fmaf(h, w.w, acc.w);
}

// ---- argmax combine steps (value desc, index asc on ties) ----
template<int CTRL>
DEV int dpp_mov(int v) {
    return __builtin_amdgcn_update_dpp(v, v, CTRL, 0xF, 0xF, false);
}
template<int CTRL>
DEV void red_step_dpp(float& bv, int& bi) {
    float ov = __builtin_bit_cast(float, dpp_mov<CTRL>(__builtin_bit_cast(int, bv)));
    int   oi = dpp_mov<CTRL>(bi);
    if (ov > bv || (ov == bv && oi < bi)) { bv = ov; bi = oi; }
}
// full 64-lane argmax; result valid in lane 63
DEV void wave_argmax(float& bv, int& bi) {
    red_step_dpp<0xB1>(bv, bi);    // quad_perm xor 1
    red_step_dpp<0x4E>(bv, bi);    // quad_perm xor 2
    red_step_dpp<0x141>(bv, bi);   // row_half_mirror (xor 4)
    red_step_dpp<0x140>(bv, bi);   // row_mirror (xor 8)
    red_step_dpp<0x142>(bv, bi);   // row_bcast15
    red_step_dpp<0x143>(bv, bi);   // row_bcast31 -> lane 63 has full result
}

// ---- single-wave FPS over LDS points (no barriers) ----
template<int N, int NPOINT>
DEV void fps_wave64(const float4* pts, float* sout, int lane) {
    constexpr int K = (N + 63) / 64;
    float rx[K], ry[K], rz[K], d[K];
#pragma unroll
    for (int k = 0; k < K; ++k) {
        const float4 c = pts[lane + k * 64];
        rx[k] = c.x; ry[k] = c.y; rz[k] = c.z; d[k] = 1e10f;
    }
    const float4 c0 = pts[0];
    float cx = c0.x, cy = c0.y, cz = c0.z;
    for (int s = 0; s < NPOINT; ++s) {
        if (lane == 0) { sout[s * 3 + 0] = cx; sout[s * 3 + 1] = cy; sout[s * 3 + 2] = cz; }
        float bestv = -1.0f; int besti = 0x7fffffff;
#pragma unroll
        for (int k = 0; k < K; ++k) {
            float d2 = sqdist(rx[k] - cx, ry[k] - cy, rz[k] - cz);
            d[k] = fminf(d[k], d2);
            if (d[k] > bestv) { bestv = d[k]; besti = lane + k * 64; }
        }
        wave_argmax(bestv, besti);
        const int far = __builtin_amdgcn_readlane(besti, 63);
        const float4 c = pts[far];
        cx = c.x; cy = c.y; cz = c.z;
    }
}

// ---------------- Fused FPS (all 3 stages) — R8 config (measured ~290us) ----
__global__ __launch_bounds__(256)
void fps_fused_kernel(const float* __restrict__ pc,
                      float* __restrict__ nxyz1, float* __restrict__ nxyz2,
                      float* __restrict__ nxyz3)
{
    constexpr int N1 = 4096, NP1 = 256, NP2 = 64, NP3 = 16, T = 256, NW = T / 64;
    constexpr int K = N1 / T;
    __shared__ float4 pxyz[N1];
    __shared__ float  sout1[NP1 * 3];
    __shared__ float  sout2[NP2 * 3];
    __shared__ float  sout3[NP3 * 3];
    __shared__ float  rv[2][NW];
    __shared__ int    ri[2][NW];

    const int b = blockIdx.x, tid = threadIdx.x;
    const int w = tid >> 6, lane = tid & 63;
    const float* base = pc + (size_t)b * N1 * 6;

    float rx[K], ry[K], rz[K], d[K];
#pragma unroll
    for (int k = 0; k < K; ++k) {
        const int p = tid + k * T;
        const float x = base[p * 6 + 0];
        const float y = base[p * 6 + 1];
        const float z = base[p * 6 + 2];
        pxyz[p] = make_float4(x, y, z, 0.f);
        rx[k] = x; ry[k] = y; rz[k] = z;
        d[k] = 1e10f;
    }
    __syncthreads();

    // ---- stage 1 ----
    {
        const float4 c0 = pxyz[0];
        float cx = c0.x, cy = c0.y, cz = c0.z;
        for (int s = 0; s < NP1; ++s) {
            if (tid == 0) { sout1[s * 3 + 0] = cx; sout1[s * 3 + 1] = cy; sout1[s * 3 + 2] = cz; }
            float bestv = -1.0f; int besti = 0x7fffffff;
#pragma unroll
            for (int k = 0; k < K; ++k) {
                float d2 = sqdist(rx[k] - cx, ry[k] - cy, rz[k] - cz);
                d[k] = fminf(d[k], d2);
                if (d[k] > bestv) { bestv = d[k]; besti = tid + k * T; }  // k asc => lowest p
            }
            wave_argmax(bestv, besti);

            const int par = s & 1;
            if (lane == 63) { rv[par][w] = bestv; ri[par][w] = besti; }
            __syncthreads();
            float bvv = rv[par][0]; int bii = ri[par][0];
#pragma unroll
            for (int q = 1; q < NW; ++q) {
                const float qv = rv[par][q]; const int qi = ri[par][q];
                if (qv > bvv || (qv == bvv && qi < bii)) { bvv = qv; bii = qi; }
            }
            const float4 c = pxyz[bii];
            cx = c.x; cy = c.y; cz = c.z;
        }
    }

    // ---- stages 2 + 3 on wave 0 ----
    if (w == 0) {
        for (int i = lane; i < NP1; i += 64)
            pxyz[i] = make_float4(sout1[i * 3 + 0], sout1[i * 3 + 1], sout1[i * 3 + 2], 0.f);
        fps_wave64<NP1, NP2>(pxyz, sout2, lane);
        for (int i = lane; i < NP2; i += 64)
            pxyz[i] = make_float4(sout2[i * 3 + 0], sout2[i * 3 + 1], sout2[i * 3 + 2], 0.f);
        fps_wave64<NP2, NP3>(pxyz, sout3, lane);
    }
    __syncthreads();

    float* o1 = nxyz1 + (size_t)b * NP1 * 3;
    for (int i = tid; i < NP1 * 3; i += T) o1[i] = sout1[i];
    float* o2 = nxyz2 + (size_t)b * NP2 * 3;
    if (tid < NP2 * 3) o2[tid] = sout2[tid];
    float* o3 = nxyz3 + (size_t)b * NP3 * 3;
    if (tid < NP3 * 3) o3[tid] = sout3[tid];
}

// ---------------- Ball query -----------------
template<int N, int NSAMP, int STRIDE>
__global__ __launch_bounds__(256)
void bq_kernel(const float* __restrict__ xyz, const float* __restrict__ newxyz,
               int* __restrict__ gidx, float r2, int S, int total)
{
    const int wid = blockIdx.x * 4 + (threadIdx.x >> 6);
    if (wid >= total) return;
    const int lane = threadIdx.x & 63;
    const int b = wid / S;
    const float cx = newxyz[(size_t)wid * 3 + 0];
    const float cy = newxyz[(size_t)wid * 3 + 1];
    const float cz = newxyz[(size_t)wid * 3 + 2];
    const float* base = xyz + (size_t)b * N * STRIDE;
    int* out = gidx + (size_t)wid * NSAMP;

    int count = 0, first = N - 1;
    constexpr int NCH = (N + 63) / 64;
    for (int ch = 0; ch < NCH; ++ch) {
        int p = ch * 64 + lane;
        bool pred = false;
        if (N % 64 == 0 || p < N) {
            float dx = base[p * STRIDE + 0] - cx;
            float dy = base[p * STRIDE + 1] - cy;
            float dz = base[p * STRIDE + 2] - cz;
            pred = sqdist(dx, dy, dz) < r2;
        }
        unsigned long long m = __ballot(pred);
        if (m) {
            if (count == 0) first = ch * 64 + __builtin_ctzll(m);
            int pos = count + __popcll(m & ((1ull << lane) - 1ull));
            if (pred && pos < NSAMP) out[pos] = p;
            count += __popcll(m);
            if (count >= NSAMP) break;
        }
    }
    if (count > NSAMP) count = NSAMP;
    for (int pos = count + lane; pos < NSAMP; pos += 64) out[pos] = first;
}

// ---------------- Grouped 2-layer MLP + maxpool -----------------
// MODE 0: stage1 (xyz stride 6, feats = pc permuted). MODE 1: feats array.
// Phase A gather is register-prefetched: chunk c+1's global loads are issued
// right after chunk c's publish barrier, hiding L2 latency under c's FMAs.
// Phase B: 8pts x 8ch tiles where geometry fits; else 4pts x 8ch.
template<int NS, int CIN, int C1, int C2, int NSRC, int MODE>
__global__ __launch_bounds__(256)
void sa_mlp2_kernel(const float* __restrict__ sxyz, const float* __restrict__ sfeat,
                    const float* __restrict__ newxyz, const int* __restrict__ gidx,
                    const float* __restrict__ W1, const float* __restrict__ B1v,
                    const float* __restrict__ W2, const float* __restrict__ B2v,
                    float* __restrict__ outf, int S)
{
    constexpr int T    = 256;
    constexpr int KCC  = (CIN < 32) ? CIN : 32;            // k-chunk length
    constexpr int KCP0 = ((KCC + 3) / 4) * 4 + 4;
    constexpr int KCP  = ((KCP0 / 4) % 2 == 0) ? KCP0 + 4 : KCP0;  // odd quad stride
    constexpr int NPT  = NS / 4;
    constexpr int NCT1 = C1 / 4;
    constexpr int TPT  = (NPT * NCT1) / T;                 // phase-A tiles per thread
    constexpr int C1P  = C1 + 4;
    constexpr int CT2  = C2 / 8;                           // phase-B: 8 channels/thread
    constexpr int PTS  = ((NS / 8) * CT2 == T) ? 8 : 4;    // points per phase-B tile
    constexpr int PB   = T / CT2;                          // parallel point-groups
    constexpr int JP   = (PTS == 8) ? 1 : (NPT / PB);      // ptiles per thread (PTS=4)
    constexpr int GRP  = (PTS == 8) ? (NS / 8) : PB;       // #groups writing mpart
    constexpr int PREG = (NS * KCC + T - 1) / T;           // prefetch regs per thread
    constexpr int XS   = (MODE == 0) ? 6 : 3;
    constexpr int CF   = CIN - 3;
    static_assert(NS % 4 == 0 && C1 % 4 == 0 && C2 % 8 == 0, "");
    static_assert((NPT * NCT1) % T == 0 && TPT >= 1, "");
    static_assert(PTS == 8 || (T % CT2 == 0 && NPT % PB == 0 && JP >= 1), "");

    __shared__ float xgc[NS][KCP];
    __shared__ __align__(16) float h1s[NS][C1P];
    __shared__ int   gix[NS];
    __shared__ float mpart[(GRP > 1) ? GRP * C2 : 8];

    const int g   = blockIdx.x;
    const int b   = g / S;
    const int tid = threadIdx.x;

    float ctr0 = 0.f, ctr1 = 0.f, ctr2 = 0.f;
    ctr0 = newxyz[(size_t)g * 3 + 0];
    ctr1 = newxyz[(size_t)g * 3 + 1];
    ctr2 = newxyz[(size_t)g * 3 + 2];
    for (int i = tid; i < NS; i += T) gix[i] = gidx[(size_t)g * NS + i];
    __syncthreads();

    const int nchunk = (CIN + KCC - 1) / KCC;

    // gather one chunk's assigned elements into registers (no LDS writes)
    float pre[PREG];
    auto load_chunk = [&](int cch) {
        const int k0 = cch * KCC;
        const int kcLen = (CIN - k0 < KCC) ? (CIN - k0) : KCC;
#pragma unroll
        for (int j = 0; j < PREG; ++j) {
            const int idx = tid + j * T;
            if (idx < NS * kcLen) {
                const int p = idx / kcLen, kk = idx - p * kcLen, k = k0 + kk;
                float v;
                const int gi = gix[p];
                if (k < 3) {
                    const float c = (k == 0) ? ctr0 : ((k == 1) ? ctr1 : ctr2);
                    v = sxyz[((size_t)b * NSRC + gi) * XS + k] - c;
                } else if constexpr (MODE == 0) {
                    const int j2 = k - 3;
                    v = sfeat[((size_t)b * NSRC + gi) * 6 + (j2 < 3 ? 3 + j2 : j2 - 3)];
                } else {
                    v = sfeat[((size_t)b * NSRC + gi) * CF + (k - 3)];
                }
                pre[j] = v;
            }
        }
    };

    // ---- Phase A: layer 1, K-chunked, acc in registers, prefetched gather ----
    float4 acc[TPT][4];
#pragma unroll
    for (int j = 0; j < TPT; ++j) {
        const int tl = tid + j * T;
        const int ct = tl % NCT1;
        const float4 bb = *(const float4*)&B1v[ct * 4];
#pragma unroll
        for (int i = 0; i < 4; ++i) acc[j][i] = bb;
    }

    load_chunk(0);
    for (int cch = 0; cch < nchunk; ++cch) {
        const int k0 = cch * KCC;
        const int kcLen = (CIN - k0 < KCC) ? (CIN - k0) : KCC;
        // publish prefetched chunk to LDS
#pragma unroll
        for (int j = 0; j < PREG; ++j) {
            const int idx = tid + j * T;
            if (idx < NS * kcLen) {
                const int p = idx / kcLen, kk = idx - p * kcLen;
                xgc[p][kk] = pre[j];
            }
        }
        __syncthreads();
        // issue next chunk's loads early; latency hides under this chunk's FMAs
        if (cch + 1 < nchunk) load_chunk(cch + 1);
        // compute chunk
#pragma unroll
        for (int j = 0; j < TPT; ++j) {
            const int tl = tid + j * T;
            const int pt = tl / NCT1, ct = tl % NCT1;
            const int p0 = pt * 4, c0 = ct * 4;
            int kk = 0;
            for (; kk + 4 <= kcLen; kk += 4) {
                const float4 xa = *(const float4*)&xgc[p0 + 0][kk];
                const float4 xb = *(const float4*)&xgc[p0 + 1][kk];
                const float4 xc = *(const float4*)&xgc[p0 + 2][kk];
                const float4 xd = *(const float4*)&xgc[p0 + 3][kk];
                const float4 w0 = *(const float4*)&W1[(size_t)(k0 + kk + 0) * C1 + c0];
                const float4 w1 = *(const float4*)&W1[(size_t)(k0 + kk + 1) * C1 + c0];
                const float4 w2 = *(const float4*)&W1[(size_t)(k0 + kk + 2) * C1 + c0];
                const float4 w3 = *(const float4*)&W1[(size_t)(k0 + kk + 3) * C1 + c0];
                fma4(acc[j][0], xa.x, w0); fma4(acc[j][0], xa.y, w1); fma4(acc[j][0], xa.z, w2); fma4(acc[j][0], xa.w, w3);
                fma4(acc[j][1], xb.x, w0); fma4(acc[j][1], xb.y, w1); fma4(acc[j][1], xb.z, w2); fma4(acc[j][1], xb.w, w3);
                fma4(acc[j][2], xc.x, w0); fma4(acc[j][2], xc.y, w1); fma4(acc[j][2], xc.z, w2); fma4(acc[j][2], xc.w, w3);
                fma4(acc[j][3], xd.x, w0); fma4(acc[j][3], xd.y, w1); fma4(acc[j][3], xd.z, w2); fma4(acc[j][3], xd.w, w3);
            }
            for (; kk < kcLen; ++kk) {
                const float4 w = *(const float4*)&W1[(size_t)(k0 + kk) * C1 + c0];
                fma4(acc[j][0], xgc[p0 + 0][kk], w);
                fma4(acc[j][1], xgc[p0 + 1][kk], w);
                fma4(acc[j][2], xgc[p0 + 2][kk], w);
                fma4(acc[j][3], xgc[p0 + 3][kk], w);
            }
        }
        __syncthreads();   // all reads of xgc done before next publish
    }
    // write h1 (relu)
#pragma unroll
    for (int j = 0; j < TPT; ++j) {
        const int tl = tid + j * T;
        const int pt = tl / NCT1, ct = tl % NCT1;
        const int p0 = pt * 4, c0 = ct * 4;
#pragma unroll
        for (int i = 0; i < 4; ++i) {
            float4 r;
            r.x = fmaxf(acc[j][i].x, 0.f); r.y = fmaxf(acc[j][i].y, 0.f);
            r.z = fmaxf(acc[j][i].z, 0.f); r.w = fmaxf(acc[j][i].w, 0.f);
            *(float4*)&h1s[p0 + i][c0] = r;
        }
    }
    __syncthreads();

    // ---- Phase B: layer 2 + maxpool ----
    if constexpr (PTS == 8) {
        const int ct = tid % CT2, pb = tid / CT2;
        const int c0 = ct * 8;
        const int p0 = pb * 8;
        const float4 bbA = *(const float4*)&B2v[c0];
        const float4 bbB = *(const float4*)&B2v[c0 + 4];
        float4 aA[8], aB[8];
#pragma unroll
        for (int i = 0; i < 8; ++i) { aA[i] = bbA; aB[i] = bbB; }
#pragma unroll 2
        for (int k = 0; k < C1; k += 4) {
            float4 h[8];
#pragma unroll
            for (int i = 0; i < 8; ++i) h[i] = *(const float4*)&h1s[p0 + i][k];
            const float4 w0A = *(const float4*)&W2[(size_t)(k + 0) * C2 + c0];
            const float4 w0B = *(const float4*)&W2[(size_t)(k + 0) * C2 + c0 + 4];
            const float4 w1A = *(const float4*)&W2[(size_t)(k + 1) * C2 + c0];
            const float4 w1B = *(const float4*)&W2[(size_t)(k + 1) * C2 + c0 + 4];
            const float4 w2A = *(const float4*)&W2[(size_t)(k + 2) * C2 + c0];
            const float4 w2B = *(const float4*)&W2[(size_t)(k + 2) * C2 + c0 + 4];
            const float4 w3A = *(const float4*)&W2[(size_t)(k + 3) * C2 + c0];
            const float4 w3B = *(const float4*)&W2[(size_t)(k + 3) * C2 + c0 + 4];
#pragma unroll
            for (int i = 0; i < 8; ++i) {
                fma4(aA[i], h[i].x, w0A); fma4(aA[i], h[i].y, w1A);
                fma4(aA[i], h[i].z, w2A); fma4(aA[i], h[i].w, w3A);
                fma4(aB[i], h[i].x, w0B); fma4(aB[i], h[i].y, w1B);
                fma4(aB[i], h[i].z, w2B); fma4(aB[i], h[i].w, w3B);
            }
        }
        float4 mA = make_float4(0.f, 0.f, 0.f, 0.f);   // relu>=0
        float4 mB = make_float4(0.f, 0.f, 0.f, 0.f);
#pragma unroll
        for (int i = 0; i < 8; ++i) {
            mA.x = fmaxf(mA.x, aA[i].x); mA.y = fmaxf(mA.y, aA[i].y);
            mA.z = fmaxf(mA.z, aA[i].z); mA.w = fmaxf(mA.w, aA[i].w);
            mB.x = fmaxf(mB.x, aB[i].x); mB.y = fmaxf(mB.y, aB[i].y);
            mB.z = fmaxf(mB.z, aB[i].z); mB.w = fmaxf(mB.w, aB[i].w);
        }
        if constexpr (GRP == 1) {
            *(float4*)&outf[(size_t)g * C2 + c0] = mA;
            *(float4*)&outf[(size_t)g * C2 + c0 + 4] = mB;
        } else {
            *(float4*)&mpart[pb * C2 + c0] = mA;
            *(float4*)&mpart[pb * C2 + c0 + 4] = mB;
            __syncthreads();
            for (int c = tid; c < C2; c += T) {
                float mm = mpart[c];
#pragma unroll
                for (int q = 1; q < GRP; ++q) mm = fmaxf(mm, mpart[q * C2 + c]);
                outf[(size_t)g * C2 + c] = mm;
            }
        }
    } else {
        const int ct = tid % CT2, pb = tid / CT2;
        const int c0 = ct * 8;
        const float4 bbA = *(const float4*)&B2v[c0];
        const float4 bbB = *(const float4*)&B2v[c0 + 4];
        float4 mA = make_float4(0.f, 0.f, 0.f, 0.f);   // relu>=0
        float4 mB = make_float4(0.f, 0.f, 0.f, 0.f);
#pragma unroll
        for (int jp = 0; jp < JP; ++jp) {
            const int p0 = (pb + jp * PB) * 4;
            float4 a0A = bbA, a1A = bbA, a2A = bbA, a3A = bbA;
            float4 a0B = bbB, a1B = bbB, a2B = bbB, a3B = bbB;
#pragma unroll 2
            for (int k = 0; k < C1; k += 4) {
                const float4 hA = *(const float4*)&h1s[p0 + 0][k];
                const float4 hB = *(const float4*)&h1s[p0 + 1][k];
                const float4 hC = *(const float4*)&h1s[p0 + 2][k];
                const float4 hD = *(const float4*)&h1s[p0 + 3][k];
                const float4 w0A = *(const float4*)&W2[(size_t)(k + 0) * C2 + c0];
                const float4 w0B = *(const float4*)&W2[(size_t)(k + 0) * C2 + c0 + 4];
                const float4 w1A = *(const float4*)&W2[(size_t)(k + 1) * C2 + c0];
                const float4 w1B = *(const float4*)&W2[(size_t)(k + 1) * C2 + c0 + 4];
                const float4 w2A = *(const float4*)&W2[(size_t)(k + 2) * C2 + c0];
                const float4 w2B = *(const float4*)&W2[(size_t)(k + 2) * C2 + c0 + 4];
                const float4 w3A = *(const float4*)&W2[(size_t)(k + 3) * C2 + c0];
                const float4 w3B = *(const float4*)&W2[(size_t)(k + 3) * C2 + c0 + 4];
                fma4(a0A, hA.x, w0A); fma4(a0A, hA.y, w1A); fma4(a0A, hA.z, w2A); fma4(a0A, hA.w, w3A);
                fma4(a0B, hA.x, w0B); fma4(a0B, hA.y, w1B); fma4(a0B, hA.z, w2B); fma4(a0B, hA.w, w3B);
                fma4(a1A, hB.x, w0A); fma4(a1A, hB.y, w1A); fma4(a1A, hB.z, w2A); fma4(a1A, hB.w, w3A);
                fma4(a1B, hB.x, w0B); fma4(a1B, hB.y, w1B); fma4(a1B, hB.z, w2B); fma4(a1B, hB.w, w3B);
                fma4(a2A, hC.x, w0A); fma4(a2A, hC.y, w1A); fma4(a2A, hC.z, w2A); fma4(a2A, hC.w, w3A);
                fma4(a2B, hC.x, w0B); fma4(a2B, hC.y, w1B); fma4(a2B, hC.z, w2B); fma4(a2B, hC.w, w3B);
                fma4(a3A, hD.x, w0A); fma4(a3A, hD.y, w1A); fma4(a3A, hD.z, w2A); fma4(a3A, hD.w, w3A);
                fma4(a3B, hD.x, w0B); fma4(a3B, hD.y, w1B); fma4(a3B, hD.z, w2B); fma4(a3B, hD.w, w3B);
            }
            mA.x = fmaxf(mA.x, fmaxf(fmaxf(a0A.x, a1A.x), fmaxf(a2A.x, a3A.x)));
            mA.y = fmaxf(mA.y, fmaxf(fmaxf(a0A.y, a1A.y), fmaxf(a2A.y, a3A.y)));
            mA.z = fmaxf(mA.z, fmaxf(fmaxf(a0A.z, a1A.z), fmaxf(a2A.z, a3A.z)));
            mA.w = fmaxf(mA.w, fmaxf(fmaxf(a0A.w, a1A.w), fmaxf(a2A.w, a3A.w)));
            mB.x = fmaxf(mB.x, fmaxf(fmaxf(a0B.x, a1B.x), fmaxf(a2B.x, a3B.x)));
            mB.y = fmaxf(mB.y, fmaxf(fmaxf(a0B.y, a1B.y), fmaxf(a2B.y, a3B.y)));
            mB.z = fmaxf(mB.z, fmaxf(fmaxf(a0B.z, a1B.z), fmaxf(a2B.z, a3B.z)));
            mB.w = fmaxf(mB.w, fmaxf(fmaxf(a0B.w, a1B.w), fmaxf(a2B.w, a3B.w)));
        }
        if constexpr (PB == 1) {
            *(float4*)&outf[(size_t)g * C2 + c0] = mA;
            *(float4*)&outf[(size_t)g * C2 + c0 + 4] = mB;
        } else {
            *(float4*)&mpart[pb * C2 + c0] = mA;
            *(float4*)&mpart[pb * C2 + c0 + 4] = mB;
            __syncthreads();
            for (int c = tid; c < C2; c += T) {
                float mm = mpart[c];
#pragma unroll
                for (int q = 1; q < GRP; ++q) mm = fmaxf(mm, mpart[q * C2 + c]);
                outf[(size_t)g * C2 + c] = mm;
            }
        }
    }
}

// ---------------- Head part 1: 4 points per block, 515->512->1024 MLP ----
__global__ __launch_bounds__(256)
void head1_kernel(const float* __restrict__ nxyz3, const float* __restrict__ feats3,
                  const float* __restrict__ w4a, const float* __restrict__ b4a,
                  const float* __restrict__ w4b, const float* __restrict__ b4b,
                  float* __restrict__ h4)
{
    const int g0  = blockIdx.x * 4;   // 4 consecutive (b,point) groups
    const int tid = threadIdx.x;
    __shared__ float xrow[4][516];
    __shared__ float h1s[4][512];
    for (int i = tid; i < 4 * 515; i += 256) {
        const int p = i / 515, k = i - p * 515;
        xrow[p][k] = (k < 3) ? nxyz3[(size_t)(g0 + p) * 3 + k]
                             : feats3[(size_t)(g0 + p) * 512 + (k - 3)];
    }
    __syncthreads();
#pragma unroll
    for (int cc = 0; cc < 2; ++cc) {
        const int c = tid + cc * 256;
        const float bb = b4a[c];
        float a0 = bb, a1 = bb, a2 = bb, a3 = bb;
#pragma unroll 4
        for (int k = 0; k < 515; ++k) {
            const float w = w4a[(size_t)k * 512 + c];
            a0 = fmaf(xrow[0][k], w, a0);
            a1 = fmaf(xrow[1][k], w, a1);
            a2 = fmaf(xrow[2][k], w, a2);
            a3 = fmaf(xrow[3][k], w, a3);
        }
        h1s[0][c] = fmaxf(a0, 0.f); h1s[1][c] = fmaxf(a1, 0.f);
        h1s[2][c] = fmaxf(a2, 0.f); h1s[3][c] = fmaxf(a3, 0.f);
    }
    __syncthreads();
    {
        const int c0 = tid * 4;
        const float4 bb = *(const float4*)&b4b[c0];
        float4 a0 = bb, a1 = bb, a2 = bb, a3 = bb;
#pragma unroll 4
        for (int k = 0; k < 512; ++k) {
            const float4 w = *(const float4*)&w4b[(size_t)k * 1024 + c0];
            fma4(a0, h1s[0][k], w);
            fma4(a1, h1s[1][k], w);
            fma4(a2, h1s[2][k], w);
            fma4(a3, h1s[3][k], w);
        }
        float4 r;
        r.x = fmaxf(a0.x, 0.f); r.y = fmaxf(a0.y, 0.f); r.z = fmaxf(a0.z, 0.f); r.w = fmaxf(a0.w, 0.f);
        *(float4*)&h4[(size_t)(g0 + 0) * 1024 + c0] = r;
        r.x = fmaxf(a1.x, 0.f); r.y = fmaxf(a1.y, 0.f); r.z = fmaxf(a1.z, 0.f); r.w = fmaxf(a1.w, 0.f);
        *(float4*)&h4[(size_t)(g0 + 1) * 1024 + c0] = r;
        r.x = fmaxf(a2.x, 0.f); r.y = fmaxf(a2.y, 0.f); r.z = fmaxf(a2.z, 0.f); r.w = fmaxf(a2.w, 0.f);
        *(float4*)&h4[(size_t)(g0 + 2) * 1024 + c0] = r;
        r.x = fmaxf(a3.x, 0.f); r.y = fmaxf(a3.y, 0.f); r.z = fmaxf(a3.z, 0.f); r.w = fmaxf(a3.w, 0.f);
        *(float4*)&h4[(size_t)(g0 + 3) * 1024 + c0] = r;
    }
}

// ---------------- Head part 2: maxpool(16) -> fc1(relu) -> fc2 -> bn-ish ----
__global__ __launch_bounds__(256)
void head2_kernel(const float* __restrict__ h4,
                  const float* __restrict__ fc1w, const float* __restrict__ fc1b,
                  const float* __restrict__ fc2w, const float* __restrict__ fc2b,
                  const float* __restrict__ gamma, const float* __restrict__ beta,
                  float* __restrict__ out)
{
    const int b   = blockIdx.x;
    const int tid = threadIdx.x;
    __shared__ float gm[1024], g1[1024];
    {
        const int c0 = tid * 4;
        float4 m = *(const float4*)&h4[((size_t)b * 16 + 0) * 1024 + c0];
#pragma unroll
        for (int p = 1; p < 16; ++p) {
            const float4 v = *(const float4*)&h4[((size_t)b * 16 + p) * 1024 + c0];
            m.x = fmaxf(m.x, v.x); m.y = fmaxf(m.y, v.y);
            m.z = fmaxf(m.z, v.z); m.w = fmaxf(m.w, v.w);
        }
        *(float4*)&gm[c0] = m;
    }
    __syncthreads();
    {
        const int c0 = tid * 4;
        float4 a = *(const float4*)&fc1b[c0];
#pragma unroll 4
        for (int k = 0; k < 1024; ++k) {
            const float4 w = *(const float4*)&fc1w[(size_t)k * 1024 + c0];
            fma4(a, gm[k], w);
        }
        g1[c0 + 0] = fmaxf(a.x, 0.f); g1[c0 + 1] = fmaxf(a.y, 0.f);
        g1[c0 + 2] = fmaxf(a.z, 0.f); g1[c0 + 3] = fmaxf(a.w, 0.f);
    }
    __syncthreads();
    if (tid < 128) {
        const float s = sqrtf(1.00001f);
        const int c = tid;
        float a = fc2b[c];
#pragma unroll 4
        for (int k = 0; k < 1024; ++k) a = fmaf(g1[k], fc2w[(size_t)k * 128 + c], a);
        out[(size_t)b * 128 + c] = (a / s) * gamma[c] + beta[c];
    }
}

// ---------------------------------------------------------------------------
extern "C" void kernel_launch(void* const* d_in, const int* in_sizes, int n_in,
                              void* d_out, int out_size, void* d_ws, size_t ws_size,
                              hipStream_t stream)
{
    const float* pc   = (const float*)d_in[0];
    const float* w1a  = (const float*)d_in[1];  const float* b1a = (const float*)d_in[2];
    const float* w1b  = (const float*)d_in[3];  const float* b1b = (const float*)d_in[4];
    const float* w2a  = (const float*)d_in[5];  const float* b2a = (const float*)d_in[6];
    const float* w2b  = (const float*)d_in[7];  const float* b2b = (const float*)d_in[8];
    const float* w3a  = (const float*)d_in[9];  const float* b3a = (const float*)d_in[10];
    const float* w3b  = (const float*)d_in[11]; const float* b3b = (const float*)d_in[12];
    const float* w4a  = (const float*)d_in[13]; const float* b4a = (const float*)d_in[14];
    const float* w4b  = (const float*)d_in[15]; const float* b4b = (const float*)d_in[16];
    const float* fc1w = (const float*)d_in[17]; const float* fc1b = (const float*)d_in[18];
    const float* fc2w = (const float*)d_in[19]; const float* fc2b = (const float*)d_in[20];
    const float* gam  = (const float*)d_in[21]; const float* bet  = (const float*)d_in[22];
    float* out = (float*)d_out;

    char* ws = (char*)d_ws;
    size_t off = 0;
    auto alloc = [&](size_t bytes) -> void* {
        void* p = ws + off;
        off = (off + bytes + 255) & ~(size_t)255;
        return p;
    };
    float* nxyz1  = (float*)alloc((size_t)32 * 256 * 3 * 4);
    int*   gidx1  = (int*)  alloc((size_t)32 * 256 * 64 * 4);
    float* feats1 = (float*)alloc((size_t)32 * 256 * 128 * 4);
    float* nxyz2  = (float*)alloc((size_t)32 * 64 * 3 * 4);
    int*   gidx2  = (int*)  alloc((size_t)32 * 64 * 64 * 4);
    float* feats2 = (float*)alloc((size_t)32 * 64 * 256 * 4);
    float* nxyz3  = (float*)alloc((size_t)32 * 16 * 3 * 4);
    int*   gidx3  = (int*)  alloc((size_t)32 * 16 * 32 * 4);
    float* feats3 = (float*)alloc((size_t)32 * 16 * 512 * 4);
    float* h4     = (float*)alloc((size_t)32 * 16 * 1024 * 4);

    const float r2a = (float)(0.1 * 0.1);
    const float r2b = (float)(0.2 * 0.2);
    const float r2c = (float)(0.4 * 0.4);

    // ---- All three FPS stages fused (one block per batch, 4-wave config) ----
    fps_fused_kernel<<<32, 256, 0, stream>>>(pc, nxyz1, nxyz2, nxyz3);

    // ---- Ball queries ----
    bq_kernel<4096, 64, 6><<<(32 * 256 + 3) / 4, 256, 0, stream>>>(pc, nxyz1, gidx1, r2a, 256, 32 * 256);
    bq_kernel<256, 64, 3><<<(32 * 64 + 3) / 4, 256, 0, stream>>>(nxyz1, nxyz2, gidx2, r2b, 64, 32 * 64);
    bq_kernel<64, 32, 3><<<(32 * 16 + 3) / 4, 256, 0, stream>>>(nxyz2, nxyz3, gidx3, r2c, 16, 32 * 16);

    // ---- SA MLPs ----
    sa_mlp2_kernel<64, 9, 64, 128, 4096, 0><<<32 * 256, 256, 0, stream>>>(
        pc, pc, nxyz1, gidx1, w1a, b1a, w1b, b1b, feats1, 256);
    sa_mlp2_kernel<64, 131, 128, 256, 256, 1><<<32 * 64, 256, 0, stream>>>(
        nxyz1, feats1, nxyz2, gidx2, w2a, b2a, w2b, b2b, feats2, 64);
    sa_mlp2_kernel<32, 259, 256, 512, 64, 1><<<32 * 16, 256, 0, stream>>>(
        nxyz2, feats2, nxyz3, gidx3, w3a, b3a, w3b, b3b, feats3, 16);

    // ---- Head: 4 points per block (128 blocks), then maxpool+fc in head2
    head1_kernel<<<32 * 16 / 4, 256, 0, stream>>>(nxyz3, feats3, w4a, b4a, w4b, b4b, h4);
    head2_kernel<<<32, 256, 0, stream>>>(h4, fc1w, fc1b, fc2w, fc2b, gam, bet, out);
}

// Round 14
// 1018.655 us; speedup vs baseline: 1.0092x; 1.0092x over previous
//
#include <hip/hip_runtime.h>

#define DEV static __device__ __forceinline__

DEV float sqdist(float dx, float dy, float dz) {
    // ((dx*dx + dy*dy) + dz*dz) with no FMA contraction — must match numpy f32
    return __fadd_rn(__fadd_rn(__fmul_rn(dx, dx), __fmul_rn(dy, dy)), __fmul_rn(dz, dz));
}

DEV void fma4(float4& acc, float h, const float4& w) {
    acc.x = fmaf(h, w.x, acc.x); acc.y = fmaf(h, w.y, acc.y);
    acc.z = fmaf(h, w.z, acc.z); acc.w = fmaf(h, w.w, acc.w);
}

// ---- argmax combine steps (value desc, index asc on ties) ----
template<int CTRL>
DEV int dpp_mov(int v) {
    return __builtin_amdgcn_update_dpp(v, v, CTRL, 0xF, 0xF, false);
}
template<int CTRL>
DEV void red_step_dpp(float& bv, int& bi) {
    float ov = __builtin_bit_cast(float, dpp_mov<CTRL>(__builtin_bit_cast(int, bv)));
    int   oi = dpp_mov<CTRL>(bi);
    if (ov > bv || (ov == bv && oi < bi)) { bv = ov; bi = oi; }
}
// full 64-lane argmax; result valid in lane 63
DEV void wave_argmax(float& bv, int& bi) {
    red_step_dpp<0xB1>(bv, bi);    // quad_perm xor 1
    red_step_dpp<0x4E>(bv, bi);    // quad_perm xor 2
    red_step_dpp<0x141>(bv, bi);   // row_half_mirror (xor 4)
    red_step_dpp<0x140>(bv, bi);   // row_mirror (xor 8)
    red_step_dpp<0x142>(bv, bi);   // row_bcast15
    red_step_dpp<0x143>(bv, bi);   // row_bcast31 -> lane 63 has full result
}

// ---- single-wave FPS over LDS points (no barriers) ----
template<int N, int NPOINT>
DEV void fps_wave64(const float4* pts, float* sout, int lane) {
    constexpr int K = (N + 63) / 64;
    float rx[K], ry[K], rz[K], d[K];
#pragma unroll
    for (int k = 0; k < K; ++k) {
        const float4 c = pts[lane + k * 64];
        rx[k] = c.x; ry[k] = c.y; rz[k] = c.z; d[k] = 1e10f;
    }
    const float4 c0 = pts[0];
    float cx = c0.x, cy = c0.y, cz = c0.z;
    for (int s = 0; s < NPOINT; ++s) {
        if (lane == 0) { sout[s * 3 + 0] = cx; sout[s * 3 + 1] = cy; sout[s * 3 + 2] = cz; }
        float bestv = -1.0f; int besti = 0x7fffffff;
#pragma unroll
        for (int k = 0; k < K; ++k) {
            float d2 = sqdist(rx[k] - cx, ry[k] - cy, rz[k] - cz);
            d[k] = fminf(d[k], d2);
            if (d[k] > bestv) { bestv = d[k]; besti = lane + k * 64; }
        }
        wave_argmax(bestv, besti);
        const int far = __builtin_amdgcn_readlane(besti, 63);
        const float4 c = pts[far];
        cx = c.x; cy = c.y; cz = c.z;
    }
}

// ---------------- Fused FPS (all 3 stages) — R8 config (measured ~290us) ----
__global__ __launch_bounds__(256)
void fps_fused_kernel(const float* __restrict__ pc,
                      float* __restrict__ nxyz1, float* __restrict__ nxyz2,
                      float* __restrict__ nxyz3)
{
    constexpr int N1 = 4096, NP1 = 256, NP2 = 64, NP3 = 16, T = 256, NW = T / 64;
    constexpr int K = N1 / T;
    __shared__ float4 pxyz[N1];
    __shared__ float  sout1[NP1 * 3];
    __shared__ float  sout2[NP2 * 3];
    __shared__ float  sout3[NP3 * 3];
    __shared__ float  rv[2][NW];
    __shared__ int    ri[2][NW];

    const int b = blockIdx.x, tid = threadIdx.x;
    const int w = tid >> 6, lane = tid & 63;
    const float* base = pc + (size_t)b * N1 * 6;

    float rx[K], ry[K], rz[K], d[K];
#pragma unroll
    for (int k = 0; k < K; ++k) {
        const int p = tid + k * T;
        const float x = base[p * 6 + 0];
        const float y = base[p * 6 + 1];
        const float z = base[p * 6 + 2];
        pxyz[p] = make_float4(x, y, z, 0.f);
        rx[k] = x; ry[k] = y; rz[k] = z;
        d[k] = 1e10f;
    }
    __syncthreads();

    // ---- stage 1 ----
    {
        const float4 c0 = pxyz[0];
        float cx = c0.x, cy = c0.y, cz = c0.z;
        for (int s = 0; s < NP1; ++s) {
            if (tid == 0) { sout1[s * 3 + 0] = cx; sout1[s * 3 + 1] = cy; sout1[s * 3 + 2] = cz; }
            float bestv = -1.0f; int besti = 0x7fffffff;
#pragma unroll
            for (int k = 0; k < K; ++k) {
                float d2 = sqdist(rx[k] - cx, ry[k] - cy, rz[k] - cz);
                d[k] = fminf(d[k], d2);
                if (d[k] > bestv) { bestv = d[k]; besti = tid + k * T; }  // k asc => lowest p
            }
            wave_argmax(bestv, besti);

            const int par = s & 1;
            if (lane == 63) { rv[par][w] = bestv; ri[par][w] = besti; }
            __syncthreads();
            float bvv = rv[par][0]; int bii = ri[par][0];
#pragma unroll
            for (int q = 1; q < NW; ++q) {
                const float qv = rv[par][q]; const int qi = ri[par][q];
                if (qv > bvv || (qv == bvv && qi < bii)) { bvv = qv; bii = qi; }
            }
            const float4 c = pxyz[bii];
            cx = c.x; cy = c.y; cz = c.z;
        }
    }

    // ---- stages 2 + 3 on wave 0 ----
    if (w == 0) {
        for (int i = lane; i < NP1; i += 64)
            pxyz[i] = make_float4(sout1[i * 3 + 0], sout1[i * 3 + 1], sout1[i * 3 + 2], 0.f);
        fps_wave64<NP1, NP2>(pxyz, sout2, lane);
        for (int i = lane; i < NP2; i += 64)
            pxyz[i] = make_float4(sout2[i * 3 + 0], sout2[i * 3 + 1], sout2[i * 3 + 2], 0.f);
        fps_wave64<NP2, NP3>(pxyz, sout3, lane);
    }
    __syncthreads();

    float* o1 = nxyz1 + (size_t)b * NP1 * 3;
    for (int i = tid; i < NP1 * 3; i += T) o1[i] = sout1[i];
    float* o2 = nxyz2 + (size_t)b * NP2 * 3;
    if (tid < NP2 * 3) o2[tid] = sout2[tid];
    float* o3 = nxyz3 + (size_t)b * NP3 * 3;
    if (tid < NP3 * 3) o3[tid] = sout3[tid];
}

// ---------------- Ball query -----------------
template<int N, int NSAMP, int STRIDE>
__global__ __launch_bounds__(256)
void bq_kernel(const float* __restrict__ xyz, const float* __restrict__ newxyz,
               int* __restrict__ gidx, float r2, int S, int total)
{
    const int wid = blockIdx.x * 4 + (threadIdx.x >> 6);
    if (wid >= total) return;
    const int lane = threadIdx.x & 63;
    const int b = wid / S;
    const float cx = newxyz[(size_t)wid * 3 + 0];
    const float cy = newxyz[(size_t)wid * 3 + 1];
    const float cz = newxyz[(size_t)wid * 3 + 2];
    const float* base = xyz + (size_t)b * N * STRIDE;
    int* out = gidx + (size_t)wid * NSAMP;

    int count = 0, first = N - 1;
    constexpr int NCH = (N + 63) / 64;
    for (int ch = 0; ch < NCH; ++ch) {
        int p = ch * 64 + lane;
        bool pred = false;
        if (N % 64 == 0 || p < N) {
            float dx = base[p * STRIDE + 0] - cx;
            float dy = base[p * STRIDE + 1] - cy;
            float dz = base[p * STRIDE + 2] - cz;
            pred = sqdist(dx, dy, dz) < r2;
        }
        unsigned long long m = __ballot(pred);
        if (m) {
            if (count == 0) first = ch * 64 + __builtin_ctzll(m);
            int pos = count + __popcll(m & ((1ull << lane) - 1ull));
            if (pred && pos < NSAMP) out[pos] = p;
            count += __popcll(m);
            if (count >= NSAMP) break;
        }
    }
    if (count > NSAMP) count = NSAMP;
    for (int pos = count + lane; pos < NSAMP; pos += 64) out[pos] = first;
}

// ---------------- Grouped 2-layer MLP + maxpool -----------------
// MODE 0: stage1 (xyz stride 6, feats = pc permuted). MODE 1: feats array.
// Phase B: unified CHB=4 register tile, PTSB = NS/GRP points per thread with
// GRP = T/(C2/4) parallel groups — minimizes per-block W2 re-streaming
// (the confirmed R11 mechanism). h1s reads are wave-broadcast for CT2>=32.
template<int NS, int CIN, int C1, int C2, int NSRC, int MODE>
__global__ __launch_bounds__(256)
void sa_mlp2_kernel(const float* __restrict__ sxyz, const float* __restrict__ sfeat,
                    const float* __restrict__ newxyz, const int* __restrict__ gidx,
                    const float* __restrict__ W1, const float* __restrict__ B1v,
                    const float* __restrict__ W2, const float* __restrict__ B2v,
                    float* __restrict__ outf, int S)
{
    constexpr int T    = 256;
    constexpr int KCC  = (CIN < 32) ? CIN : 32;            // k-chunk length
    constexpr int KCP0 = ((KCC + 3) / 4) * 4 + 4;
    constexpr int KCP  = ((KCP0 / 4) % 2 == 0) ? KCP0 + 4 : KCP0;  // odd quad stride
    constexpr int NPT  = NS / 4;
    constexpr int NCT1 = C1 / 4;
    constexpr int TPT  = (NPT * NCT1) / T;                 // phase-A tiles per thread
    constexpr int C1P  = C1 + 4;
    constexpr int CT2  = C2 / 4;                           // phase-B: 4 channels/thread
    constexpr int GRP  = T / CT2;                          // parallel point-groups
    constexpr int PTSB = NS / GRP;                         // points per thread
    constexpr int XS   = (MODE == 0) ? 6 : 3;
    constexpr int CF   = CIN - 3;
    static_assert(NS % 4 == 0 && C1 % 4 == 0 && C2 % 4 == 0, "");
    static_assert((NPT * NCT1) % T == 0 && TPT >= 1, "");
    static_assert(T % CT2 == 0 && NS % GRP == 0 && PTSB >= 1, "");

    __shared__ float xgc[NS][KCP];
    __shared__ __align__(16) float h1s[NS][C1P];
    __shared__ int   gix[NS];
    __shared__ float mpart[(GRP > 1) ? GRP * C2 : 4];

    const int g   = blockIdx.x;
    const int b   = g / S;
    const int tid = threadIdx.x;

    float ctr0 = 0.f, ctr1 = 0.f, ctr2 = 0.f;
    ctr0 = newxyz[(size_t)g * 3 + 0];
    ctr1 = newxyz[(size_t)g * 3 + 1];
    ctr2 = newxyz[(size_t)g * 3 + 2];
    for (int i = tid; i < NS; i += T) gix[i] = gidx[(size_t)g * NS + i];
    __syncthreads();

    // ---- Phase A: layer 1, K-chunked, accumulators in registers ----
    float4 acc[TPT][4];
#pragma unroll
    for (int j = 0; j < TPT; ++j) {
        const int tl = tid + j * T;
        const int ct = tl % NCT1;
        const float4 bb = *(const float4*)&B1v[ct * 4];
#pragma unroll
        for (int i = 0; i < 4; ++i) acc[j][i] = bb;
    }

    const int nchunk = (CIN + KCC - 1) / KCC;
    for (int cch = 0; cch < nchunk; ++cch) {
        const int k0 = cch * KCC;
        const int kcLen = (CIN - k0 < KCC) ? (CIN - k0) : KCC;
        if (cch > 0) __syncthreads();
        // gather chunk
        for (int idx = tid; idx < NS * kcLen; idx += T) {
            const int p = idx / kcLen, kk = idx - p * kcLen, k = k0 + kk;
            float v;
            const int gi = gix[p];
            if (k < 3) {
                const float c = (k == 0) ? ctr0 : ((k == 1) ? ctr1 : ctr2);
                v = sxyz[((size_t)b * NSRC + gi) * XS + k] - c;
            } else if constexpr (MODE == 0) {
                const int j2 = k - 3;
                v = sfeat[((size_t)b * NSRC + gi) * 6 + (j2 < 3 ? 3 + j2 : j2 - 3)];
            } else {
                v = sfeat[((size_t)b * NSRC + gi) * CF + (k - 3)];
            }
            xgc[p][kk] = v;
        }
        __syncthreads();
        // compute chunk
#pragma unroll
        for (int j = 0; j < TPT; ++j) {
            const int tl = tid + j * T;
            const int pt = tl / NCT1, ct = tl % NCT1;
            const int p0 = pt * 4, c0 = ct * 4;
            int kk = 0;
            for (; kk + 4 <= kcLen; kk += 4) {
                const float4 xa = *(const float4*)&xgc[p0 + 0][kk];
                const float4 xb = *(const float4*)&xgc[p0 + 1][kk];
                const float4 xc = *(const float4*)&xgc[p0 + 2][kk];
                const float4 xd = *(const float4*)&xgc[p0 + 3][kk];
                const float4 w0 = *(const float4*)&W1[(size_t)(k0 + kk + 0) * C1 + c0];
                const float4 w1 = *(const float4*)&W1[(size_t)(k0 + kk + 1) * C1 + c0];
                const float4 w2 = *(const float4*)&W1[(size_t)(k0 + kk + 2) * C1 + c0];
                const float4 w3 = *(const float4*)&W1[(size_t)(k0 + kk + 3) * C1 + c0];
                fma4(acc[j][0], xa.x, w0); fma4(acc[j][0], xa.y, w1); fma4(acc[j][0], xa.z, w2); fma4(acc[j][0], xa.w, w3);
                fma4(acc[j][1], xb.x, w0); fma4(acc[j][1], xb.y, w1); fma4(acc[j][1], xb.z, w2); fma4(acc[j][1], xb.w, w3);
                fma4(acc[j][2], xc.x, w0); fma4(acc[j][2], xc.y, w1); fma4(acc[j][2], xc.z, w2); fma4(acc[j][2], xc.w, w3);
                fma4(acc[j][3], xd.x, w0); fma4(acc[j][3], xd.y, w1); fma4(acc[j][3], xd.z, w2); fma4(acc[j][3], xd.w, w3);
            }
            for (; kk < kcLen; ++kk) {
                const float4 w = *(const float4*)&W1[(size_t)(k0 + kk) * C1 + c0];
                fma4(acc[j][0], xgc[p0 + 0][kk], w);
                fma4(acc[j][1], xgc[p0 + 1][kk], w);
                fma4(acc[j][2], xgc[p0 + 2][kk], w);
                fma4(acc[j][3], xgc[p0 + 3][kk], w);
            }
        }
    }
    // write h1 (relu)
    __syncthreads();
#pragma unroll
    for (int j = 0; j < TPT; ++j) {
        const int tl = tid + j * T;
        const int pt = tl / NCT1, ct = tl % NCT1;
        const int p0 = pt * 4, c0 = ct * 4;
#pragma unroll
        for (int i = 0; i < 4; ++i) {
            float4 r;
            r.x = fmaxf(acc[j][i].x, 0.f); r.y = fmaxf(acc[j][i].y, 0.f);
            r.z = fmaxf(acc[j][i].z, 0.f); r.w = fmaxf(acc[j][i].w, 0.f);
            *(float4*)&h1s[p0 + i][c0] = r;
        }
    }
    __syncthreads();

    // ---- Phase B: layer 2 + maxpool, PTSB pts x 4 ch per thread ----
    {
        const int ct = tid % CT2, pb = tid / CT2;
        const int c0 = ct * 4;
        const int p0 = pb * PTSB;
        const float4 bb = *(const float4*)&B2v[c0];
        float4 ac[PTSB];
#pragma unroll
        for (int i = 0; i < PTSB; ++i) ac[i] = bb;
#pragma unroll 2
        for (int k = 0; k < C1; k += 4) {
            const float4 w0 = *(const float4*)&W2[(size_t)(k + 0) * C2 + c0];
            const float4 w1 = *(const float4*)&W2[(size_t)(k + 1) * C2 + c0];
            const float4 w2 = *(const float4*)&W2[(size_t)(k + 2) * C2 + c0];
            const float4 w3 = *(const float4*)&W2[(size_t)(k + 3) * C2 + c0];
#pragma unroll
            for (int i = 0; i < PTSB; ++i) {
                const float4 h = *(const float4*)&h1s[p0 + i][k];
                fma4(ac[i], h.x, w0); fma4(ac[i], h.y, w1);
                fma4(ac[i], h.z, w2); fma4(ac[i], h.w, w3);
            }
        }
        float4 m = make_float4(0.f, 0.f, 0.f, 0.f);   // relu>=0
#pragma unroll
        for (int i = 0; i < PTSB; ++i) {
            m.x = fmaxf(m.x, ac[i].x); m.y = fmaxf(m.y, ac[i].y);
            m.z = fmaxf(m.z, ac[i].z); m.w = fmaxf(m.w, ac[i].w);
        }
        if constexpr (GRP == 1) {
            *(float4*)&outf[(size_t)g * C2 + c0] = m;
        } else {
            *(float4*)&mpart[pb * C2 + c0] = m;
            __syncthreads();
            for (int c = tid; c < C2; c += T) {
                float mm = mpart[c];
#pragma unroll
                for (int q = 1; q < GRP; ++q) mm = fmaxf(mm, mpart[q * C2 + c]);
                outf[(size_t)g * C2 + c] = mm;
            }
        }
    }
}

// ---------------- Head part 1: 4 points per block, 515->512->1024 MLP ----
__global__ __launch_bounds__(256)
void head1_kernel(const float* __restrict__ nxyz3, const float* __restrict__ feats3,
                  const float* __restrict__ w4a, const float* __restrict__ b4a,
                  const float* __restrict__ w4b, const float* __restrict__ b4b,
                  float* __restrict__ h4)
{
    const int g0  = blockIdx.x * 4;   // 4 consecutive (b,point) groups
    const int tid = threadIdx.x;
    __shared__ float xrow[4][516];
    __shared__ float h1s[4][512];
    for (int i = tid; i < 4 * 515; i += 256) {
        const int p = i / 515, k = i - p * 515;
        xrow[p][k] = (k < 3) ? nxyz3[(size_t)(g0 + p) * 3 + k]
                             : feats3[(size_t)(g0 + p) * 512 + (k - 3)];
    }
    __syncthreads();
#pragma unroll
    for (int cc = 0; cc < 2; ++cc) {
        const int c = tid + cc * 256;
        const float bb = b4a[c];
        float a0 = bb, a1 = bb, a2 = bb, a3 = bb;
#pragma unroll 4
        for (int k = 0; k < 515; ++k) {
            const float w = w4a[(size_t)k * 512 + c];
            a0 = fmaf(xrow[0][k], w, a0);
            a1 = fmaf(xrow[1][k], w, a1);
            a2 = fmaf(xrow[2][k], w, a2);
            a3 = fmaf(xrow[3][k], w, a3);
        }
        h1s[0][c] = fmaxf(a0, 0.f); h1s[1][c] = fmaxf(a1, 0.f);
        h1s[2][c] = fmaxf(a2, 0.f); h1s[3][c] = fmaxf(a3, 0.f);
    }
    __syncthreads();
    {
        const int c0 = tid * 4;
        const float4 bb = *(const float4*)&b4b[c0];
        float4 a0 = bb, a1 = bb, a2 = bb, a3 = bb;
#pragma unroll 4
        for (int k = 0; k < 512; ++k) {
            const float4 w = *(const float4*)&w4b[(size_t)k * 1024 + c0];
            fma4(a0, h1s[0][k], w);
            fma4(a1, h1s[1][k], w);
            fma4(a2, h1s[2][k], w);
            fma4(a3, h1s[3][k], w);
        }
        float4 r;
        r.x = fmaxf(a0.x, 0.f); r.y = fmaxf(a0.y, 0.f); r.z = fmaxf(a0.z, 0.f); r.w = fmaxf(a0.w, 0.f);
        *(float4*)&h4[(size_t)(g0 + 0) * 1024 + c0] = r;
        r.x = fmaxf(a1.x, 0.f); r.y = fmaxf(a1.y, 0.f); r.z = fmaxf(a1.z, 0.f); r.w = fmaxf(a1.w, 0.f);
        *(float4*)&h4[(size_t)(g0 + 1) * 1024 + c0] = r;
        r.x = fmaxf(a2.x, 0.f); r.y = fmaxf(a2.y, 0.f); r.z = fmaxf(a2.z, 0.f); r.w = fmaxf(a2.w, 0.f);
        *(float4*)&h4[(size_t)(g0 + 2) * 1024 + c0] = r;
        r.x = fmaxf(a3.x, 0.f); r.y = fmaxf(a3.y, 0.f); r.z = fmaxf(a3.z, 0.f); r.w = fmaxf(a3.w, 0.f);
        *(float4*)&h4[(size_t)(g0 + 3) * 1024 + c0] = r;
    }
}

// ---------------- Head part 2: maxpool(16) -> fc1(relu) -> fc2 -> bn-ish ----
__global__ __launch_bounds__(256)
void head2_kernel(const float* __restrict__ h4,
                  const float* __restrict__ fc1w, const float* __restrict__ fc1b,
                  const float* __restrict__ fc2w, const float* __restrict__ fc2b,
                  const float* __restrict__ gamma, const float* __restrict__ beta,
                  float* __restrict__ out)
{
    const int b   = blockIdx.x;
    const int tid = threadIdx.x;
    __shared__ float gm[1024], g1[1024];
    {
        const int c0 = tid * 4;
        float4 m = *(const float4*)&h4[((size_t)b * 16 + 0) * 1024 + c0];
#pragma unroll
        for (int p = 1; p < 16; ++p) {
            const float4 v = *(const float4*)&h4[((size_t)b * 16 + p) * 1024 + c0];
            m.x = fmaxf(m.x, v.x); m.y = fmaxf(m.y, v.y);
            m.z = fmaxf(m.z, v.z); m.w = fmaxf(m.w, v.w);
        }
        *(float4*)&gm[c0] = m;
    }
    __syncthreads();
    {
        const int c0 = tid * 4;
        float4 a = *(const float4*)&fc1b[c0];
#pragma unroll 4
        for (int k = 0; k < 1024; ++k) {
            const float4 w = *(const float4*)&fc1w[(size_t)k * 1024 + c0];
            fma4(a, gm[k], w);
        }
        g1[c0 + 0] = fmaxf(a.x, 0.f); g1[c0 + 1] = fmaxf(a.y, 0.f);
        g1[c0 + 2] = fmaxf(a.z, 0.f); g1[c0 + 3] = fmaxf(a.w, 0.f);
    }
    __syncthreads();
    if (tid < 128) {
        const float s = sqrtf(1.00001f);
        const int c = tid;
        float a = fc2b[c];
#pragma unroll 4
        for (int k = 0; k < 1024; ++k) a = fmaf(g1[k], fc2w[(size_t)k * 128 + c], a);
        out[(size_t)b * 128 + c] = (a / s) * gamma[c] + beta[c];
    }
}

// ---------------------------------------------------------------------------
extern "C" void kernel_launch(void* const* d_in, const int* in_sizes, int n_in,
                              void* d_out, int out_size, void* d_ws, size_t ws_size,
                              hipStream_t stream)
{
    const float* pc   = (const float*)d_in[0];
    const float* w1a  = (const float*)d_in[1];  const float* b1a = (const float*)d_in[2];
    const float* w1b  = (const float*)d_in[3];  const float* b1b = (const float*)d_in[4];
    const float* w2a  = (const float*)d_in[5];  const float* b2a = (const float*)d_in[6];
    const float* w2b  = (const float*)d_in[7];  const float* b2b = (const float*)d_in[8];
    const float* w3a  = (const float*)d_in[9];  const float* b3a = (const float*)d_in[10];
    const float* w3b  = (const float*)d_in[11]; const float* b3b = (const float*)d_in[12];
    const float* w4a  = (const float*)d_in[13]; const float* b4a = (const float*)d_in[14];
    const float* w4b  = (const float*)d_in[15]; const float* b4b = (const float*)d_in[16];
    const float* fc1w = (const float*)d_in[17]; const float* fc1b = (const float*)d_in[18];
    const float* fc2w = (const float*)d_in[19]; const float* fc2b = (const float*)d_in[20];
    const float* gam  = (const float*)d_in[21]; const float* bet  = (const float*)d_in[22];
    float* out = (float*)d_out;

    char* ws = (char*)d_ws;
    size_t off = 0;
    auto alloc = [&](size_t bytes) -> void* {
        void* p = ws + off;
        off = (off + bytes + 255) & ~(size_t)255;
        return p;
    };
    float* nxyz1  = (float*)alloc((size_t)32 * 256 * 3 * 4);
    int*   gidx1  = (int*)  alloc((size_t)32 * 256 * 64 * 4);
    float* feats1 = (float*)alloc((size_t)32 * 256 * 128 * 4);
    float* nxyz2  = (float*)alloc((size_t)32 * 64 * 3 * 4);
    int*   gidx2  = (int*)  alloc((size_t)32 * 64 * 64 * 4);
    float* feats2 = (float*)alloc((size_t)32 * 64 * 256 * 4);
    float* nxyz3  = (float*)alloc((size_t)32 * 16 * 3 * 4);
    int*   gidx3  = (int*)  alloc((size_t)32 * 16 * 32 * 4);
    float* feats3 = (float*)alloc((size_t)32 * 16 * 512 * 4);
    float* h4     = (float*)alloc((size_t)32 * 16 * 1024 * 4);

    const float r2a = (float)(0.1 * 0.1);
    const float r2b = (float)(0.2 * 0.2);
    const float r2c = (float)(0.4 * 0.4);

    // ---- All three FPS stages fused (one block per batch, 4-wave config) ----
    fps_fused_kernel<<<32, 256, 0, stream>>>(pc, nxyz1, nxyz2, nxyz3);

    // ---- Ball queries ----
    bq_kernel<4096, 64, 6><<<(32 * 256 + 3) / 4, 256, 0, stream>>>(pc, nxyz1, gidx1, r2a, 256, 32 * 256);
    bq_kernel<256, 64, 3><<<(32 * 64 + 3) / 4, 256, 0, stream>>>(nxyz1, nxyz2, gidx2, r2b, 64, 32 * 64);
    bq_kernel<64, 32, 3><<<(32 * 16 + 3) / 4, 256, 0, stream>>>(nxyz2, nxyz3, gidx3, r2c, 16, 32 * 16);

    // ---- SA MLPs ----
    sa_mlp2_kernel<64, 9, 64, 128, 4096, 0><<<32 * 256, 256, 0, stream>>>(
        pc, pc, nxyz1, gidx1, w1a, b1a, w1b, b1b, feats1, 256);
    sa_mlp2_kernel<64, 131, 128, 256, 256, 1><<<32 * 64, 256, 0, stream>>>(
        nxyz1, feats1, nxyz2, gidx2, w2a, b2a, w2b, b2b, feats2, 64);
    sa_mlp2_kernel<32, 259, 256, 512, 64, 1><<<32 * 16, 256, 0, stream>>>(
        nxyz2, feats2, nxyz3, gidx3, w3a, b3a, w3b, b3b, feats3, 16);

    // ---- Head: 4 points per block (128 blocks), then maxpool+fc in head2
    head1_kernel<<<32 * 16 / 4, 256, 0, stream>>>(nxyz3, feats3, w4a, b4a, w4b, b4b, h4);
    head2_kernel<<<32, 256, 0, stream>>>(h4, fc1w, fc1b, fc2w, fc2b, gam, bet, out);
}